// Round 5
// baseline (329.254 us; speedup 1.0000x reference)
//
#include <hip/hip_runtime.h>

#define N_NODES 50000
#define N_EDGES 800000
#define D_FEAT  256
#define N_CLASS 40
#define NSCAN_BLOCKS ((N_NODES + 255) / 256)   // 196

typedef __attribute__((ext_vector_type(8))) short short8;
typedef __attribute__((ext_vector_type(4))) float f32x4;

__device__ __forceinline__ float bf2f(unsigned short u) {
    unsigned int x = ((unsigned int)u) << 16;
    return __builtin_bit_cast(float, x);
}
__device__ __forceinline__ unsigned short f2bf(float f) {
    unsigned int x = __builtin_bit_cast(unsigned int, f);
    x += 0x7fff + ((x >> 16) & 1);   // RTNE
    return (unsigned short)(x >> 16);
}

// ---------------- fp32 -> bf16 convert (x) ----------------
__global__ void cvt_bf16_kernel(const float* __restrict__ in, unsigned short* __restrict__ out, int n4) {
    int i = blockIdx.x * blockDim.x + threadIdx.x;
    if (i >= n4) return;
    float4 v = reinterpret_cast<const float4*>(in)[i];
    ushort4 o;
    o.x = f2bf(v.x); o.y = f2bf(v.y); o.z = f2bf(v.z); o.w = f2bf(v.w);
    reinterpret_cast<ushort4*>(out)[i] = o;
}

// ---------------- weight converts -> concatenated bf16 layouts ----------------
// w1cat: [256][512]  row c = [W1l[c][0:256] | W1r[c][0:256]]
// w2cat: [80][256]   rows 0-39 = W2l, rows 40-79 = W2r
__global__ void cvt_weights_kernel(const float* __restrict__ w1l, const float* __restrict__ w1r,
                                   const float* __restrict__ w2l, const float* __restrict__ w2r,
                                   unsigned short* __restrict__ w1cat, unsigned short* __restrict__ w2cat) {
    int i = blockIdx.x * blockDim.x + threadIdx.x;   // float4 index
    const int N1 = 256 * 128;        // 32768 float4s of w1cat
    const int N2 = 80 * 64;          // 5120 float4s of w2cat
    const float* s; unsigned short* dptr;
    if (i < N1) {
        int n = i >> 7, kq = i & 127;
        s = (kq < 64) ? (w1l + n * 256 + kq * 4) : (w1r + n * 256 + (kq - 64) * 4);
        dptr = w1cat + n * 512 + kq * 4;
    } else if (i < N1 + N2) {
        int j = i - N1;
        int n = j >> 6, kq = j & 63;
        s = (n < 40) ? (w2l + n * 256 + kq * 4) : (w2r + (n - 40) * 256 + kq * 4);
        dptr = w2cat + n * 256 + kq * 4;
    } else return;
    float4 v = *reinterpret_cast<const float4*>(s);
    ushort4 o;
    o.x = f2bf(v.x); o.y = f2bf(v.y); o.z = f2bf(v.z); o.w = f2bf(v.w);
    *reinterpret_cast<ushort4*>(dptr) = o;
}

// ---------------- degree histogram ----------------
__global__ void sage_deg_kernel(const int* __restrict__ dst, int* __restrict__ degc) {
    int e = blockIdx.x * blockDim.x + threadIdx.x;
    if (e < N_EDGES) atomicAdd(&degc[dst[e]], 1);
}

// ---------------- hierarchical scan ----------------
__global__ __launch_bounds__(256)
void scan_local_kernel(const int* __restrict__ deg, int* __restrict__ escan, int* __restrict__ bsum) {
    __shared__ int s[256];
    const int t = threadIdx.x;
    const int i = blockIdx.x * 256 + t;
    const int v = (i < N_NODES) ? deg[i] : 0;
    s[t] = v;
    __syncthreads();
    #pragma unroll
    for (int off = 1; off < 256; off <<= 1) {
        int u = (t >= off) ? s[t - off] : 0;
        __syncthreads();
        s[t] += u;
        __syncthreads();
    }
    if (i < N_NODES) escan[i] = s[t] - v;
    if (t == 255) bsum[blockIdx.x] = s[255];
}

__global__ __launch_bounds__(256)
void scan_bsum_kernel(int* __restrict__ bsum, int* __restrict__ row_off) {
    __shared__ int s[256];
    const int t = threadIdx.x;
    const int v = (t < NSCAN_BLOCKS) ? bsum[t] : 0;
    s[t] = v;
    __syncthreads();
    #pragma unroll
    for (int off = 1; off < 256; off <<= 1) {
        int u = (t >= off) ? s[t - off] : 0;
        __syncthreads();
        s[t] += u;
        __syncthreads();
    }
    if (t < NSCAN_BLOCKS) bsum[t] = s[t] - v;
    if (t == 255) row_off[N_NODES] = s[255];
}

__global__ void scan_add_kernel(const int* __restrict__ escan_in, const int* __restrict__ bsum,
                                int* __restrict__ row_off, int* __restrict__ cursor) {
    const int i = blockIdx.x * 256 + threadIdx.x;
    if (i >= N_NODES) return;
    const int v = escan_in[i] + bsum[blockIdx.x];
    row_off[i] = v;
    cursor[i] = v;
}

// ---------------- CSR fill ----------------
__global__ void sage_fill_kernel(const int* __restrict__ src, const int* __restrict__ dst,
                                 int* __restrict__ cursor, int* __restrict__ csr) {
    int e = blockIdx.x * blockDim.x + threadIdx.x;
    if (e >= N_EDGES) return;
    int pos = atomicAdd(&cursor[dst[e]], 1);
    csr[pos] = src[e];
}

// ---------------- bf16 gather-aggregate + mean (256-dim, layer 1) ----------------
__global__ __launch_bounds__(256)
void sage_gather_kernel(const unsigned short* __restrict__ feat,
                        const int* __restrict__ row_off,
                        const int* __restrict__ csr,
                        unsigned short* __restrict__ agg) {
    const int tid = threadIdx.x;
    const int lane = tid & 63;
    const int node = blockIdx.x * 8 + (tid >> 6) * 2 + (lane >> 5);
    const int c8 = (lane & 31) * 8;
    if (node >= N_NODES) return;
    const int k0 = row_off[node];
    const int k1 = row_off[node + 1];
    float a[8] = {};
    for (int k = k0; k < k1; ++k) {
        const int s = csr[k];
        short8 v = *reinterpret_cast<const short8*>(feat + (size_t)s * D_FEAT + c8);
        #pragma unroll
        for (int j = 0; j < 8; ++j) a[j] += bf2f((unsigned short)v[j]);
    }
    const float sc = 1.0f / fmaxf((float)(k1 - k0), 1.0f);
    short8 o;
    #pragma unroll
    for (int j = 0; j < 8; ++j) o[j] = (short)f2bf(a[j] * sc);
    *reinterpret_cast<short8*>(agg + (size_t)node * D_FEAT + c8) = o;
}

// ---------------- GEMM1: h = relu([agg|x] @ w1cat^T + b1l + b1r), bf16 out ----------------
// No LDS, no barriers. Block = 4 waves stacked on M (256 rows); wave = 64x64 tile.
// Grid: 784 linear blocks, XCD-swizzled; decode x = t/4 (row-block), y = t%4 (col-block).
__global__ __launch_bounds__(256)
void sage_gemm1_kernel(const unsigned short* __restrict__ agg,
                       const unsigned short* __restrict__ xb,
                       const unsigned short* __restrict__ w1cat,
                       const float* __restrict__ b1l, const float* __restrict__ b1r,
                       unsigned short* __restrict__ h) {
    // bijective XCD swizzle (784 % 8 == 0): each XCD gets 98 consecutive logical tiles
    const int t = (blockIdx.x & 7) * 98 + (blockIdx.x >> 3);
    const int xblk = t >> 2;
    const int yblk = t & 3;

    const int tid = threadIdx.x;
    const int wid = tid >> 6;
    const int lane = tid & 63;
    const int l15 = lane & 15, l4 = lane >> 4;
    const int r0 = xblk * 256 + wid * 64;
    const int c0 = yblk * 64;

    int arow[4];
    #pragma unroll
    for (int mi = 0; mi < 4; ++mi) {
        int r = r0 + mi * 16 + l15;
        arow[mi] = (r < N_NODES) ? r : (N_NODES - 1);
    }

    f32x4 acc[4][4] = {};

    #pragma unroll 4
    for (int kt = 0; kt < 512; kt += 32) {
        const unsigned short* __restrict__ Asrc = (kt < 256) ? agg : xb;
        const int kk = (kt & 255) + l4 * 8;
        short8 a[4], b[4];
        #pragma unroll
        for (int mi = 0; mi < 4; ++mi)
            a[mi] = *reinterpret_cast<const short8*>(Asrc + (size_t)arow[mi] * D_FEAT + kk);
        #pragma unroll
        for (int ni = 0; ni < 4; ++ni)
            b[ni] = *reinterpret_cast<const short8*>(w1cat + (size_t)(c0 + ni * 16 + l15) * 512 + kt + l4 * 8);
        #pragma unroll
        for (int mi = 0; mi < 4; ++mi)
            #pragma unroll
            for (int ni = 0; ni < 4; ++ni)
                acc[mi][ni] = __builtin_amdgcn_mfma_f32_16x16x32_bf16(a[mi], b[ni], acc[mi][ni], 0, 0, 0);
    }

    #pragma unroll
    for (int ni = 0; ni < 4; ++ni) {
        const int c = c0 + ni * 16 + l15;
        const float bias = b1l[c] + b1r[c];
        #pragma unroll
        for (int mi = 0; mi < 4; ++mi) {
            #pragma unroll
            for (int i = 0; i < 4; ++i) {
                const int r = r0 + mi * 16 + l4 * 4 + i;
                if (r >= N_NODES) continue;
                h[(size_t)r * D_FEAT + c] = f2bf(fmaxf(acc[mi][ni][i] + bias, 0.f));
            }
        }
    }
}

// ---------------- GEMM2: u = h@W2l^T (fp32), v = h@W2r^T + b2l + b2r (fp32) ----------------
// wave = 64 rows x 80 cols (4x5 frags); block = 4 waves = 256 rows; grid 196.
__global__ __launch_bounds__(256)
void sage_gemm2_kernel(const unsigned short* __restrict__ hb,
                       const unsigned short* __restrict__ w2cat,
                       const float* __restrict__ b2l, const float* __restrict__ b2r,
                       float* __restrict__ u, float* __restrict__ v) {
    const int tid = threadIdx.x;
    const int wid = tid >> 6;
    const int lane = tid & 63;
    const int l15 = lane & 15, l4 = lane >> 4;
    const int r0 = blockIdx.x * 256 + wid * 64;

    int arow[4];
    #pragma unroll
    for (int mi = 0; mi < 4; ++mi) {
        int r = r0 + mi * 16 + l15;
        arow[mi] = (r < N_NODES) ? r : (N_NODES - 1);
    }

    f32x4 acc[4][5] = {};

    #pragma unroll 4
    for (int kt = 0; kt < 256; kt += 32) {
        const int kk = kt + l4 * 8;
        short8 a[4], b[5];
        #pragma unroll
        for (int mi = 0; mi < 4; ++mi)
            a[mi] = *reinterpret_cast<const short8*>(hb + (size_t)arow[mi] * D_FEAT + kk);
        #pragma unroll
        for (int ni = 0; ni < 5; ++ni)
            b[ni] = *reinterpret_cast<const short8*>(w2cat + (size_t)(ni * 16 + l15) * 256 + kk);
        #pragma unroll
        for (int mi = 0; mi < 4; ++mi)
            #pragma unroll
            for (int ni = 0; ni < 5; ++ni)
                acc[mi][ni] = __builtin_amdgcn_mfma_f32_16x16x32_bf16(a[mi], b[ni], acc[mi][ni], 0, 0, 0);
    }

    #pragma unroll
    for (int ni = 0; ni < 5; ++ni) {
        const int c = ni * 16 + l15;             // 0..79
        const bool is_u = (c < N_CLASS);
        const float bias = is_u ? 0.f : (b2l[c - N_CLASS] + b2r[c - N_CLASS]);
        #pragma unroll
        for (int mi = 0; mi < 4; ++mi) {
            #pragma unroll
            for (int i = 0; i < 4; ++i) {
                const int r = r0 + mi * 16 + l4 * 4 + i;
                if (r >= N_NODES) continue;
                const float val = acc[mi][ni][i] + bias;
                if (is_u) u[(size_t)r * N_CLASS + c] = val;
                else      v[(size_t)r * N_CLASS + (c - N_CLASS)] = val;
            }
        }
    }
}

// ---------------- gather2: out = agg(u) + v  (40-dim) ----------------
__global__ __launch_bounds__(256)
void sage_gather2_kernel(const float* __restrict__ u, const float* __restrict__ v,
                         const int* __restrict__ row_off, const int* __restrict__ csr,
                         float* __restrict__ out) {
    const int node = blockIdx.x * 4 + (threadIdx.x >> 6);
    const int lane = threadIdx.x & 63;
    if (node >= N_NODES || lane >= N_CLASS) return;
    const int k0 = row_off[node];
    const int k1 = row_off[node + 1];
    float a = 0.f;
    for (int k = k0; k < k1; ++k)
        a += u[(size_t)csr[k] * N_CLASS + lane];
    const float sc = 1.0f / fmaxf((float)(k1 - k0), 1.0f);
    out[(size_t)node * N_CLASS + lane] = a * sc + v[(size_t)node * N_CLASS + lane];
}

extern "C" void kernel_launch(void* const* d_in, const int* in_sizes, int n_in,
                              void* d_out, int out_size, void* d_ws, size_t ws_size,
                              hipStream_t stream) {
    const float* x    = (const float*)d_in[0];
    const int*   ei   = (const int*)d_in[1];
    const float* w1l  = (const float*)d_in[2];
    const float* b1l  = (const float*)d_in[3];
    const float* w1r  = (const float*)d_in[4];
    const float* b1r  = (const float*)d_in[5];
    const float* w2l  = (const float*)d_in[6];
    const float* b2l  = (const float*)d_in[7];
    const float* w2r  = (const float*)d_in[8];
    const float* b2r  = (const float*)d_in[9];
    float* out = (float*)d_out;

    const int* src = ei;
    const int* dst = ei + N_EDGES;

    // workspace layout (bytes)
    const size_t FEAT_BYTES  = (size_t)N_NODES * D_FEAT * 2;           // 25.6 MB
    const size_t ROW_OFF_OFF = 0;
    const size_t CURSOR_OFF  = 204800;
    const size_t BSUM_OFF    = 409600;
    const size_t CSR_OFF     = 410624;
    const size_t XB_OFF      = CSR_OFF + (size_t)N_EDGES * 4 + 1024;   // 3,611,648
    const size_t AGG_OFF     = XB_OFF + FEAT_BYTES;
    const size_t H_OFF       = AGG_OFF + FEAT_BYTES;
    const size_t W1C_OFF     = H_OFF + FEAT_BYTES;                     // 262144 B
    const size_t W2C_OFF     = W1C_OFF + 262144;                       // 40960 B
    const size_t U_OFF       = W2C_OFF + 40960;                        // 8 MB
    const size_t V_OFF       = U_OFF + (size_t)N_NODES * N_CLASS * 4;  // 8 MB

    int* row_off = (int*)((char*)d_ws + ROW_OFF_OFF);
    int* cursor  = (int*)((char*)d_ws + CURSOR_OFF);
    int* bsum    = (int*)((char*)d_ws + BSUM_OFF);
    int* csr     = (int*)((char*)d_ws + CSR_OFF);
    unsigned short* xb    = (unsigned short*)((char*)d_ws + XB_OFF);
    unsigned short* aggb  = (unsigned short*)((char*)d_ws + AGG_OFF);
    unsigned short* hb    = (unsigned short*)((char*)d_ws + H_OFF);
    unsigned short* w1cat = (unsigned short*)((char*)d_ws + W1C_OFF);
    unsigned short* w2cat = (unsigned short*)((char*)d_ws + W2C_OFF);
    float* u = (float*)((char*)d_ws + U_OFF);
    float* v = (float*)((char*)d_ws + V_OFF);

    const int eblocks = (N_EDGES + 255) / 256;     // 3125
    const int gblocks = (N_NODES + 7) / 8;         // 6250

    // ---- converts ----
    cvt_bf16_kernel<<<(N_NODES * D_FEAT / 4 + 255) / 256, 256, 0, stream>>>(x, xb, N_NODES * D_FEAT / 4);
    cvt_weights_kernel<<<148, 256, 0, stream>>>(w1l, w1r, w2l, w2r, w1cat, w2cat);

    // ---- CSR build ----
    hipMemsetAsync(cursor, 0, (size_t)N_NODES * 4, stream);
    sage_deg_kernel<<<eblocks, 256, 0, stream>>>(dst, cursor);
    scan_local_kernel<<<NSCAN_BLOCKS, 256, 0, stream>>>(cursor, row_off, bsum);
    scan_bsum_kernel<<<1, 256, 0, stream>>>(bsum, row_off);
    scan_add_kernel<<<NSCAN_BLOCKS, 256, 0, stream>>>(row_off, bsum, row_off, cursor);
    sage_fill_kernel<<<eblocks, 256, 0, stream>>>(src, dst, cursor, csr);

    // ---- layer 1 ----
    sage_gather_kernel<<<gblocks, 256, 0, stream>>>(xb, row_off, csr, aggb);
    sage_gemm1_kernel<<<784, 256, 0, stream>>>(aggb, xb, w1cat, b1l, b1r, hb);

    // ---- layer 2 (transform-then-aggregate) ----
    sage_gemm2_kernel<<<196, 256, 0, stream>>>(hb, w2cat, b2l, b2r, u, v);
    sage_gather2_kernel<<<(N_NODES + 3) / 4, 256, 0, stream>>>(u, v, row_off, csr, out);

    (void)in_sizes; (void)n_in; (void)out_size; (void)ws_size;
}

// Round 6
// 286.027 us; speedup vs baseline: 1.1511x; 1.1511x over previous
//
#include <hip/hip_runtime.h>

#define N_NODES 50000
#define N_EDGES 800000
#define D_FEAT  256
#define N_CLASS 40
#define NSCAN_BLOCKS ((N_NODES + 255) / 256)   // 196

typedef __attribute__((ext_vector_type(8))) short short8;
typedef __attribute__((ext_vector_type(4))) float f32x4;

__device__ __forceinline__ float bf2f(unsigned short u) {
    unsigned int x = ((unsigned int)u) << 16;
    return __builtin_bit_cast(float, x);
}
__device__ __forceinline__ unsigned short f2bf(float f) {
    unsigned int x = __builtin_bit_cast(unsigned int, f);
    x += 0x7fff + ((x >> 16) & 1);   // RTNE
    return (unsigned short)(x >> 16);
}

// ---------------- fp32 -> bf16 convert (x) ----------------
__global__ void cvt_bf16_kernel(const float* __restrict__ in, unsigned short* __restrict__ out, int n4) {
    int i = blockIdx.x * blockDim.x + threadIdx.x;
    if (i >= n4) return;
    float4 v = reinterpret_cast<const float4*>(in)[i];
    ushort4 o;
    o.x = f2bf(v.x); o.y = f2bf(v.y); o.z = f2bf(v.z); o.w = f2bf(v.w);
    reinterpret_cast<ushort4*>(out)[i] = o;
}

// ---------------- weight converts -> concatenated bf16 layouts ----------------
// w1cat: [256][512]  row c = [W1l[c][0:256] | W1r[c][0:256]]
// w2cat: [80][256]   rows 0-39 = W2l, rows 40-79 = W2r
__global__ void cvt_weights_kernel(const float* __restrict__ w1l, const float* __restrict__ w1r,
                                   const float* __restrict__ w2l, const float* __restrict__ w2r,
                                   unsigned short* __restrict__ w1cat, unsigned short* __restrict__ w2cat) {
    int i = blockIdx.x * blockDim.x + threadIdx.x;   // float4 index
    const int N1 = 256 * 128;
    const int N2 = 80 * 64;
    const float* s; unsigned short* dptr;
    if (i < N1) {
        int n = i >> 7, kq = i & 127;
        s = (kq < 64) ? (w1l + n * 256 + kq * 4) : (w1r + n * 256 + (kq - 64) * 4);
        dptr = w1cat + n * 512 + kq * 4;
    } else if (i < N1 + N2) {
        int j = i - N1;
        int n = j >> 6, kq = j & 63;
        s = (n < 40) ? (w2l + n * 256 + kq * 4) : (w2r + (n - 40) * 256 + kq * 4);
        dptr = w2cat + n * 256 + kq * 4;
    } else return;
    float4 v = *reinterpret_cast<const float4*>(s);
    ushort4 o;
    o.x = f2bf(v.x); o.y = f2bf(v.y); o.z = f2bf(v.z); o.w = f2bf(v.w);
    *reinterpret_cast<ushort4*>(dptr) = o;
}

// ---------------- degree histogram ----------------
__global__ void sage_deg_kernel(const int* __restrict__ dst, int* __restrict__ degc) {
    int e = blockIdx.x * blockDim.x + threadIdx.x;
    if (e < N_EDGES) atomicAdd(&degc[dst[e]], 1);
}

// ---------------- hierarchical scan ----------------
__global__ __launch_bounds__(256)
void scan_local_kernel(const int* __restrict__ deg, int* __restrict__ escan, int* __restrict__ bsum) {
    __shared__ int s[256];
    const int t = threadIdx.x;
    const int i = blockIdx.x * 256 + t;
    const int v = (i < N_NODES) ? deg[i] : 0;
    s[t] = v;
    __syncthreads();
    #pragma unroll
    for (int off = 1; off < 256; off <<= 1) {
        int u = (t >= off) ? s[t - off] : 0;
        __syncthreads();
        s[t] += u;
        __syncthreads();
    }
    if (i < N_NODES) escan[i] = s[t] - v;
    if (t == 255) bsum[blockIdx.x] = s[255];
}

__global__ __launch_bounds__(256)
void scan_bsum_kernel(int* __restrict__ bsum, int* __restrict__ row_off) {
    __shared__ int s[256];
    const int t = threadIdx.x;
    const int v = (t < NSCAN_BLOCKS) ? bsum[t] : 0;
    s[t] = v;
    __syncthreads();
    #pragma unroll
    for (int off = 1; off < 256; off <<= 1) {
        int u = (t >= off) ? s[t - off] : 0;
        __syncthreads();
        s[t] += u;
        __syncthreads();
    }
    if (t < NSCAN_BLOCKS) bsum[t] = s[t] - v;
    if (t == 255) row_off[N_NODES] = s[255];
}

__global__ void scan_add_kernel(const int* __restrict__ escan_in, const int* __restrict__ bsum,
                                int* __restrict__ row_off, int* __restrict__ cursor) {
    const int i = blockIdx.x * 256 + threadIdx.x;
    if (i >= N_NODES) return;
    const int v = escan_in[i] + bsum[blockIdx.x];
    row_off[i] = v;
    cursor[i] = v;
}

// ---------------- CSR fill ----------------
__global__ void sage_fill_kernel(const int* __restrict__ src, const int* __restrict__ dst,
                                 int* __restrict__ cursor, int* __restrict__ csr) {
    int e = blockIdx.x * blockDim.x + threadIdx.x;
    if (e >= N_EDGES) return;
    int pos = atomicAdd(&cursor[dst[e]], 1);
    csr[pos] = src[e];
}

// ---------------- bf16 gather-aggregate + mean (256-dim, layer 1) ----------------
// 2 nodes per wave, 32 lanes x 16B each; 4-way unrolled neighbor loop for MLP.
__global__ __launch_bounds__(256)
void sage_gather_kernel(const unsigned short* __restrict__ feat,
                        const int* __restrict__ row_off,
                        const int* __restrict__ csr,
                        unsigned short* __restrict__ agg) {
    const int tid = threadIdx.x;
    const int lane = tid & 63;
    const int node = blockIdx.x * 8 + (tid >> 6) * 2 + (lane >> 5);
    const int c8 = (lane & 31) * 8;
    if (node >= N_NODES) return;
    const int k0 = row_off[node];
    const int k1 = row_off[node + 1];
    float a[8] = {};
    int k = k0;
    for (; k + 4 <= k1; k += 4) {
        const int s0 = csr[k], s1 = csr[k + 1], s2 = csr[k + 2], s3 = csr[k + 3];
        short8 v0 = *reinterpret_cast<const short8*>(feat + (size_t)s0 * D_FEAT + c8);
        short8 v1 = *reinterpret_cast<const short8*>(feat + (size_t)s1 * D_FEAT + c8);
        short8 v2 = *reinterpret_cast<const short8*>(feat + (size_t)s2 * D_FEAT + c8);
        short8 v3 = *reinterpret_cast<const short8*>(feat + (size_t)s3 * D_FEAT + c8);
        #pragma unroll
        for (int j = 0; j < 8; ++j)
            a[j] += bf2f((unsigned short)v0[j]) + bf2f((unsigned short)v1[j])
                  + bf2f((unsigned short)v2[j]) + bf2f((unsigned short)v3[j]);
    }
    for (; k < k1; ++k) {
        const int s = csr[k];
        short8 v = *reinterpret_cast<const short8*>(feat + (size_t)s * D_FEAT + c8);
        #pragma unroll
        for (int j = 0; j < 8; ++j) a[j] += bf2f((unsigned short)v[j]);
    }
    const float sc = 1.0f / fmaxf((float)(k1 - k0), 1.0f);
    short8 o;
    #pragma unroll
    for (int j = 0; j < 8; ++j) o[j] = (short)f2bf(a[j] * sc);
    *reinterpret_cast<short8*>(agg + (size_t)node * D_FEAT + c8) = o;
}

// ---------------- GEMM1: h = relu([agg|x] @ w1cat^T + b1l + b1r), bf16 out ----------------
// Reg-only, no LDS/barriers. BK=128: 4 K-steps, each {32 x 16B loads -> 1 wait -> 64 MFMA}.
// Block = 4 waves on M (256 rows); wave = 64x64. Grid 784 linear, XCD-swizzled.
__global__ __launch_bounds__(256, 2)
void sage_gemm1_kernel(const unsigned short* __restrict__ agg,
                       const unsigned short* __restrict__ xb,
                       const unsigned short* __restrict__ w1cat,
                       const float* __restrict__ b1l, const float* __restrict__ b1r,
                       unsigned short* __restrict__ h) {
    const int t = (blockIdx.x & 7) * 98 + (blockIdx.x >> 3);   // bijective: 784 = 8*98
    const int xblk = t >> 2;
    const int yblk = t & 3;

    const int tid = threadIdx.x;
    const int wid = tid >> 6;
    const int lane = tid & 63;
    const int l15 = lane & 15, l4 = lane >> 4;
    const int r0 = xblk * 256 + wid * 64;
    const int c0 = yblk * 64;

    int arow[4];
    #pragma unroll
    for (int mi = 0; mi < 4; ++mi) {
        int r = r0 + mi * 16 + l15;
        arow[mi] = (r < N_NODES) ? r : (N_NODES - 1);
    }

    f32x4 acc[4][4] = {};

    #pragma unroll
    for (int step = 0; step < 4; ++step) {             // BK = 128
        const unsigned short* __restrict__ Asrc = (step < 2) ? agg : xb;
        const int kb = (step & 1) * 128 + l4 * 8;      // within the 256-col A half
        const int wb = step * 128 + l4 * 8;            // within the 512-col w1cat row
        short8 a[4][4], b[4][4];
        #pragma unroll
        for (int ks = 0; ks < 4; ++ks)
            #pragma unroll
            for (int mi = 0; mi < 4; ++mi)
                a[mi][ks] = *reinterpret_cast<const short8*>(
                    Asrc + (size_t)arow[mi] * D_FEAT + kb + ks * 32);
        #pragma unroll
        for (int ks = 0; ks < 4; ++ks)
            #pragma unroll
            for (int ni = 0; ni < 4; ++ni)
                b[ni][ks] = *reinterpret_cast<const short8*>(
                    w1cat + (size_t)(c0 + ni * 16 + l15) * 512 + wb + ks * 32);
        #pragma unroll
        for (int ks = 0; ks < 4; ++ks)
            #pragma unroll
            for (int mi = 0; mi < 4; ++mi)
                #pragma unroll
                for (int ni = 0; ni < 4; ++ni)
                    acc[mi][ni] = __builtin_amdgcn_mfma_f32_16x16x32_bf16(
                        a[mi][ks], b[ni][ks], acc[mi][ni], 0, 0, 0);
    }

    #pragma unroll
    for (int ni = 0; ni < 4; ++ni) {
        const int c = c0 + ni * 16 + l15;
        const float bias = b1l[c] + b1r[c];
        #pragma unroll
        for (int mi = 0; mi < 4; ++mi) {
            #pragma unroll
            for (int i = 0; i < 4; ++i) {
                const int r = r0 + mi * 16 + l4 * 4 + i;
                if (r >= N_NODES) continue;
                h[(size_t)r * D_FEAT + c] = f2bf(fmaxf(acc[mi][ni][i] + bias, 0.f));
            }
        }
    }
}

// ---------------- GEMM2: u = h@W2l^T, v = h@W2r^T + b2 (fp32) ----------------
// BK=128: 2 K-steps, each {36 loads -> 1 wait -> 80 MFMA}. wave = 64r x 80c.
__global__ __launch_bounds__(256, 2)
void sage_gemm2_kernel(const unsigned short* __restrict__ hb,
                       const unsigned short* __restrict__ w2cat,
                       const float* __restrict__ b2l, const float* __restrict__ b2r,
                       float* __restrict__ u, float* __restrict__ v) {
    const int tid = threadIdx.x;
    const int wid = tid >> 6;
    const int lane = tid & 63;
    const int l15 = lane & 15, l4 = lane >> 4;
    const int r0 = blockIdx.x * 256 + wid * 64;

    int arow[4];
    #pragma unroll
    for (int mi = 0; mi < 4; ++mi) {
        int r = r0 + mi * 16 + l15;
        arow[mi] = (r < N_NODES) ? r : (N_NODES - 1);
    }

    f32x4 acc[4][5] = {};

    #pragma unroll
    for (int step = 0; step < 2; ++step) {             // BK = 128
        const int kb = step * 128 + l4 * 8;
        short8 a[4][4], b[5][4];
        #pragma unroll
        for (int ks = 0; ks < 4; ++ks)
            #pragma unroll
            for (int mi = 0; mi < 4; ++mi)
                a[mi][ks] = *reinterpret_cast<const short8*>(
                    hb + (size_t)arow[mi] * D_FEAT + kb + ks * 32);
        #pragma unroll
        for (int ks = 0; ks < 4; ++ks)
            #pragma unroll
            for (int ni = 0; ni < 5; ++ni)
                b[ni][ks] = *reinterpret_cast<const short8*>(
                    w2cat + (size_t)(ni * 16 + l15) * 256 + kb + ks * 32);
        #pragma unroll
        for (int ks = 0; ks < 4; ++ks)
            #pragma unroll
            for (int mi = 0; mi < 4; ++mi)
                #pragma unroll
                for (int ni = 0; ni < 5; ++ni)
                    acc[mi][ni] = __builtin_amdgcn_mfma_f32_16x16x32_bf16(
                        a[mi][ks], b[ni][ks], acc[mi][ni], 0, 0, 0);
    }

    #pragma unroll
    for (int ni = 0; ni < 5; ++ni) {
        const int c = ni * 16 + l15;             // 0..79
        const bool is_u = (c < N_CLASS);
        const float bias = is_u ? 0.f : (b2l[c - N_CLASS] + b2r[c - N_CLASS]);
        #pragma unroll
        for (int mi = 0; mi < 4; ++mi) {
            #pragma unroll
            for (int i = 0; i < 4; ++i) {
                const int r = r0 + mi * 16 + l4 * 4 + i;
                if (r >= N_NODES) continue;
                const float val = acc[mi][ni][i] + bias;
                if (is_u) u[(size_t)r * N_CLASS + c] = val;
                else      v[(size_t)r * N_CLASS + (c - N_CLASS)] = val;
            }
        }
    }
}

// ---------------- gather2: out = agg(u) + v  (40-dim), 4-way unrolled ----------------
__global__ __launch_bounds__(256)
void sage_gather2_kernel(const float* __restrict__ u, const float* __restrict__ v,
                         const int* __restrict__ row_off, const int* __restrict__ csr,
                         float* __restrict__ out) {
    const int node = blockIdx.x * 4 + (threadIdx.x >> 6);
    const int lane = threadIdx.x & 63;
    if (node >= N_NODES || lane >= N_CLASS) return;
    const int k0 = row_off[node];
    const int k1 = row_off[node + 1];
    float a = 0.f;
    int k = k0;
    for (; k + 4 <= k1; k += 4) {
        const int s0 = csr[k], s1 = csr[k + 1], s2 = csr[k + 2], s3 = csr[k + 3];
        a += u[(size_t)s0 * N_CLASS + lane] + u[(size_t)s1 * N_CLASS + lane]
           + u[(size_t)s2 * N_CLASS + lane] + u[(size_t)s3 * N_CLASS + lane];
    }
    for (; k < k1; ++k)
        a += u[(size_t)csr[k] * N_CLASS + lane];
    const float sc = 1.0f / fmaxf((float)(k1 - k0), 1.0f);
    out[(size_t)node * N_CLASS + lane] = a * sc + v[(size_t)node * N_CLASS + lane];
}

extern "C" void kernel_launch(void* const* d_in, const int* in_sizes, int n_in,
                              void* d_out, int out_size, void* d_ws, size_t ws_size,
                              hipStream_t stream) {
    const float* x    = (const float*)d_in[0];
    const int*   ei   = (const int*)d_in[1];
    const float* w1l  = (const float*)d_in[2];
    const float* b1l  = (const float*)d_in[3];
    const float* w1r  = (const float*)d_in[4];
    const float* b1r  = (const float*)d_in[5];
    const float* w2l  = (const float*)d_in[6];
    const float* b2l  = (const float*)d_in[7];
    const float* w2r  = (const float*)d_in[8];
    const float* b2r  = (const float*)d_in[9];
    float* out = (float*)d_out;

    const int* src = ei;
    const int* dst = ei + N_EDGES;

    // workspace layout (bytes)
    const size_t FEAT_BYTES  = (size_t)N_NODES * D_FEAT * 2;           // 25.6 MB
    const size_t ROW_OFF_OFF = 0;
    const size_t CURSOR_OFF  = 204800;
    const size_t BSUM_OFF    = 409600;
    const size_t CSR_OFF     = 410624;
    const size_t XB_OFF      = CSR_OFF + (size_t)N_EDGES * 4 + 1024;   // 3,611,648
    const size_t AGG_OFF     = XB_OFF + FEAT_BYTES;
    const size_t H_OFF       = AGG_OFF + FEAT_BYTES;
    const size_t W1C_OFF     = H_OFF + FEAT_BYTES;
    const size_t W2C_OFF     = W1C_OFF + 262144;
    const size_t U_OFF       = W2C_OFF + 40960;
    const size_t V_OFF       = U_OFF + (size_t)N_NODES * N_CLASS * 4;

    int* row_off = (int*)((char*)d_ws + ROW_OFF_OFF);
    int* cursor  = (int*)((char*)d_ws + CURSOR_OFF);
    int* bsum    = (int*)((char*)d_ws + BSUM_OFF);
    int* csr     = (int*)((char*)d_ws + CSR_OFF);
    unsigned short* xb    = (unsigned short*)((char*)d_ws + XB_OFF);
    unsigned short* aggb  = (unsigned short*)((char*)d_ws + AGG_OFF);
    unsigned short* hb    = (unsigned short*)((char*)d_ws + H_OFF);
    unsigned short* w1cat = (unsigned short*)((char*)d_ws + W1C_OFF);
    unsigned short* w2cat = (unsigned short*)((char*)d_ws + W2C_OFF);
    float* u = (float*)((char*)d_ws + U_OFF);
    float* v = (float*)((char*)d_ws + V_OFF);

    const int eblocks = (N_EDGES + 255) / 256;     // 3125
    const int gblocks = (N_NODES + 7) / 8;         // 6250

    // ---- converts ----
    cvt_bf16_kernel<<<(N_NODES * D_FEAT / 4 + 255) / 256, 256, 0, stream>>>(x, xb, N_NODES * D_FEAT / 4);
    cvt_weights_kernel<<<148, 256, 0, stream>>>(w1l, w1r, w2l, w2r, w1cat, w2cat);

    // ---- CSR build ----
    hipMemsetAsync(cursor, 0, (size_t)N_NODES * 4, stream);
    sage_deg_kernel<<<eblocks, 256, 0, stream>>>(dst, cursor);
    scan_local_kernel<<<NSCAN_BLOCKS, 256, 0, stream>>>(cursor, row_off, bsum);
    scan_bsum_kernel<<<1, 256, 0, stream>>>(bsum, row_off);
    scan_add_kernel<<<NSCAN_BLOCKS, 256, 0, stream>>>(row_off, bsum, row_off, cursor);
    sage_fill_kernel<<<eblocks, 256, 0, stream>>>(src, dst, cursor, csr);

    // ---- layer 1 ----
    sage_gather_kernel<<<gblocks, 256, 0, stream>>>(xb, row_off, csr, aggb);
    sage_gemm1_kernel<<<784, 256, 0, stream>>>(aggb, xb, w1cat, b1l, b1r, hb);

    // ---- layer 2 (transform-then-aggregate) ----
    sage_gemm2_kernel<<<196, 256, 0, stream>>>(hb, w2cat, b2l, b2r, u, v);
    sage_gather2_kernel<<<(N_NODES + 3) / 4, 256, 0, stream>>>(u, v, row_off, csr, out);

    (void)in_sizes; (void)n_in; (void)out_size; (void)ws_size;
}

// Round 7
// 279.690 us; speedup vs baseline: 1.1772x; 1.0227x over previous
//
#include <hip/hip_runtime.h>

#define N_NODES 50000
#define N_EDGES 800000
#define D_FEAT  256
#define N_CLASS 40
#define NSCAN_BLOCKS ((N_NODES + 255) / 256)   // 196

typedef __attribute__((ext_vector_type(8))) short short8;
typedef __attribute__((ext_vector_type(4))) float f32x4;

#define SBAR() __builtin_amdgcn_sched_barrier(0)

__device__ __forceinline__ float bf2f(unsigned short u) {
    unsigned int x = ((unsigned int)u) << 16;
    return __builtin_bit_cast(float, x);
}
__device__ __forceinline__ unsigned short f2bf(float f) {
    unsigned int x = __builtin_bit_cast(unsigned int, f);
    x += 0x7fff + ((x >> 16) & 1);   // RTNE
    return (unsigned short)(x >> 16);
}

// ---------------- fp32 -> bf16 convert (x) ----------------
__global__ void cvt_bf16_kernel(const float* __restrict__ in, unsigned short* __restrict__ out, int n4) {
    int i = blockIdx.x * blockDim.x + threadIdx.x;
    if (i >= n4) return;
    float4 v = reinterpret_cast<const float4*>(in)[i];
    ushort4 o;
    o.x = f2bf(v.x); o.y = f2bf(v.y); o.z = f2bf(v.z); o.w = f2bf(v.w);
    reinterpret_cast<ushort4*>(out)[i] = o;
}

// ---------------- weight converts -> concatenated bf16 layouts ----------------
// w1cat: [256][512]  row c = [W1l[c][0:256] | W1r[c][0:256]]
// w2cat: [80][256]   rows 0-39 = W2l, rows 40-79 = W2r
__global__ void cvt_weights_kernel(const float* __restrict__ w1l, const float* __restrict__ w1r,
                                   const float* __restrict__ w2l, const float* __restrict__ w2r,
                                   unsigned short* __restrict__ w1cat, unsigned short* __restrict__ w2cat) {
    int i = blockIdx.x * blockDim.x + threadIdx.x;   // float4 index
    const int N1 = 256 * 128;
    const int N2 = 80 * 64;
    const float* s; unsigned short* dptr;
    if (i < N1) {
        int n = i >> 7, kq = i & 127;
        s = (kq < 64) ? (w1l + n * 256 + kq * 4) : (w1r + n * 256 + (kq - 64) * 4);
        dptr = w1cat + n * 512 + kq * 4;
    } else if (i < N1 + N2) {
        int j = i - N1;
        int n = j >> 6, kq = j & 63;
        s = (n < 40) ? (w2l + n * 256 + kq * 4) : (w2r + (n - 40) * 256 + kq * 4);
        dptr = w2cat + n * 256 + kq * 4;
    } else return;
    float4 v = *reinterpret_cast<const float4*>(s);
    ushort4 o;
    o.x = f2bf(v.x); o.y = f2bf(v.y); o.z = f2bf(v.z); o.w = f2bf(v.w);
    *reinterpret_cast<ushort4*>(dptr) = o;
}

// ---------------- degree histogram ----------------
__global__ void sage_deg_kernel(const int* __restrict__ dst, int* __restrict__ degc) {
    int e = blockIdx.x * blockDim.x + threadIdx.x;
    if (e < N_EDGES) atomicAdd(&degc[dst[e]], 1);
}

// ---------------- hierarchical scan ----------------
__global__ __launch_bounds__(256)
void scan_local_kernel(const int* __restrict__ deg, int* __restrict__ escan, int* __restrict__ bsum) {
    __shared__ int s[256];
    const int t = threadIdx.x;
    const int i = blockIdx.x * 256 + t;
    const int v = (i < N_NODES) ? deg[i] : 0;
    s[t] = v;
    __syncthreads();
    #pragma unroll
    for (int off = 1; off < 256; off <<= 1) {
        int u = (t >= off) ? s[t - off] : 0;
        __syncthreads();
        s[t] += u;
        __syncthreads();
    }
    if (i < N_NODES) escan[i] = s[t] - v;
    if (t == 255) bsum[blockIdx.x] = s[255];
}

__global__ __launch_bounds__(256)
void scan_bsum_kernel(int* __restrict__ bsum, int* __restrict__ row_off) {
    __shared__ int s[256];
    const int t = threadIdx.x;
    const int v = (t < NSCAN_BLOCKS) ? bsum[t] : 0;
    s[t] = v;
    __syncthreads();
    #pragma unroll
    for (int off = 1; off < 256; off <<= 1) {
        int u = (t >= off) ? s[t - off] : 0;
        __syncthreads();
        s[t] += u;
        __syncthreads();
    }
    if (t < NSCAN_BLOCKS) bsum[t] = s[t] - v;
    if (t == 255) row_off[N_NODES] = s[255];
}

__global__ void scan_add_kernel(const int* __restrict__ escan_in, const int* __restrict__ bsum,
                                int* __restrict__ row_off, int* __restrict__ cursor) {
    const int i = blockIdx.x * 256 + threadIdx.x;
    if (i >= N_NODES) return;
    const int v = escan_in[i] + bsum[blockIdx.x];
    row_off[i] = v;
    cursor[i] = v;
}

// ---------------- CSR fill ----------------
__global__ void sage_fill_kernel(const int* __restrict__ src, const int* __restrict__ dst,
                                 int* __restrict__ cursor, int* __restrict__ csr) {
    int e = blockIdx.x * blockDim.x + threadIdx.x;
    if (e >= N_EDGES) return;
    int pos = atomicAdd(&cursor[dst[e]], 1);
    csr[pos] = src[e];
}

// ---------------- bf16 gather-aggregate + mean (256-dim, layer 1) ----------------
// 2 nodes per wave, 32 lanes x 16B; batched 4-edge loads pinned with sched_barrier.
__global__ __launch_bounds__(256)
void sage_gather_kernel(const unsigned short* __restrict__ feat,
                        const int* __restrict__ row_off,
                        const int* __restrict__ csr,
                        unsigned short* __restrict__ agg) {
    const int tid = threadIdx.x;
    const int lane = tid & 63;
    const int node = blockIdx.x * 8 + (tid >> 6) * 2 + (lane >> 5);
    const int c8 = (lane & 31) * 8;
    if (node >= N_NODES) return;
    const int k0 = row_off[node];
    const int k1 = row_off[node + 1];
    float a[8] = {};
    int k = k0;
    for (; k + 4 <= k1; k += 4) {
        const int s0 = csr[k], s1 = csr[k + 1], s2 = csr[k + 2], s3 = csr[k + 3];
        short8 v0 = *reinterpret_cast<const short8*>(feat + (size_t)s0 * D_FEAT + c8);
        short8 v1 = *reinterpret_cast<const short8*>(feat + (size_t)s1 * D_FEAT + c8);
        short8 v2 = *reinterpret_cast<const short8*>(feat + (size_t)s2 * D_FEAT + c8);
        short8 v3 = *reinterpret_cast<const short8*>(feat + (size_t)s3 * D_FEAT + c8);
        SBAR();   // keep the 4 row-loads batched ahead of the adds
        #pragma unroll
        for (int j = 0; j < 8; ++j)
            a[j] += bf2f((unsigned short)v0[j]) + bf2f((unsigned short)v1[j])
                  + bf2f((unsigned short)v2[j]) + bf2f((unsigned short)v3[j]);
    }
    for (; k < k1; ++k) {
        const int s = csr[k];
        short8 v = *reinterpret_cast<const short8*>(feat + (size_t)s * D_FEAT + c8);
        #pragma unroll
        for (int j = 0; j < 8; ++j) a[j] += bf2f((unsigned short)v[j]);
    }
    const float sc = 1.0f / fmaxf((float)(k1 - k0), 1.0f);
    short8 o;
    #pragma unroll
    for (int j = 0; j < 8; ++j) o[j] = (short)f2bf(a[j] * sc);
    *reinterpret_cast<short8*>(agg + (size_t)node * D_FEAT + c8) = o;
}

// ---------------- GEMM1: h = relu([agg|x] @ w1cat^T + b1l + b1r), bf16 out ----------------
// Reg-only, no LDS/barriers. 8 K-steps of BK=64, explicit even/odd double buffer,
// sched_barrier(0) pins [loads | MFMA] blocks so loads stay batched & prefetched.
// Block = 4 waves on M (256 rows); wave = 64x64. Grid 784 linear, XCD-chunked.
__global__ __launch_bounds__(256, 2)
void sage_gemm1_kernel(const unsigned short* __restrict__ agg,
                       const unsigned short* __restrict__ xb,
                       const unsigned short* __restrict__ w1cat,
                       const float* __restrict__ b1l, const float* __restrict__ b1r,
                       unsigned short* __restrict__ h) {
    const int t = (blockIdx.x & 7) * 98 + (blockIdx.x >> 3);   // bijective: 784 = 8*98
    const int xblk = t >> 2;
    const int yblk = t & 3;

    const int tid = threadIdx.x;
    const int wid = tid >> 6;
    const int lane = tid & 63;
    const int l15 = lane & 15, l4 = lane >> 4;
    const int r0 = xblk * 256 + wid * 64;
    const int c0 = yblk * 64;

    int arow[4];
    #pragma unroll
    for (int mi = 0; mi < 4; ++mi) {
        int r = r0 + mi * 16 + l15;
        arow[mi] = (r < N_NODES) ? r : (N_NODES - 1);
    }

    f32x4 acc[4][4] = {};
    short8 a0[4][2], b0[4][2], a1[4][2], b1v[4][2];

#define G1_LOAD(aS, bS, s)                                                        \
    {                                                                             \
        const unsigned short* Asrc_ = ((s) < 4) ? agg : xb;                       \
        const int kb_ = ((s) & 3) * 64 + l4 * 8;                                  \
        const int wb_ = (s) * 64 + l4 * 8;                                        \
        _Pragma("unroll")                                                         \
        for (int ks = 0; ks < 2; ++ks) {                                          \
            _Pragma("unroll")                                                     \
            for (int mi = 0; mi < 4; ++mi)                                        \
                aS[mi][ks] = *reinterpret_cast<const short8*>(                    \
                    Asrc_ + (size_t)arow[mi] * D_FEAT + kb_ + ks * 32);           \
            _Pragma("unroll")                                                     \
            for (int ni = 0; ni < 4; ++ni)                                        \
                bS[ni][ks] = *reinterpret_cast<const short8*>(                    \
                    w1cat + (size_t)(c0 + ni * 16 + l15) * 512 + wb_ + ks * 32);  \
        }                                                                         \
    }

#define G1_MFMA(aS, bS)                                                           \
    _Pragma("unroll")                                                             \
    for (int ks = 0; ks < 2; ++ks)                                                \
        _Pragma("unroll")                                                         \
        for (int mi = 0; mi < 4; ++mi)                                            \
            _Pragma("unroll")                                                     \
            for (int ni = 0; ni < 4; ++ni)                                        \
                acc[mi][ni] = __builtin_amdgcn_mfma_f32_16x16x32_bf16(            \
                    aS[mi][ks], bS[ni][ks], acc[mi][ni], 0, 0, 0);

    G1_LOAD(a0, b0, 0)  SBAR();
    G1_LOAD(a1, b1v, 1) SBAR(); G1_MFMA(a0, b0)  SBAR();
    G1_LOAD(a0, b0, 2)  SBAR(); G1_MFMA(a1, b1v) SBAR();
    G1_LOAD(a1, b1v, 3) SBAR(); G1_MFMA(a0, b0)  SBAR();
    G1_LOAD(a0, b0, 4)  SBAR(); G1_MFMA(a1, b1v) SBAR();
    G1_LOAD(a1, b1v, 5) SBAR(); G1_MFMA(a0, b0)  SBAR();
    G1_LOAD(a0, b0, 6)  SBAR(); G1_MFMA(a1, b1v) SBAR();
    G1_LOAD(a1, b1v, 7) SBAR(); G1_MFMA(a0, b0)  SBAR();
    G1_MFMA(a1, b1v)
#undef G1_LOAD
#undef G1_MFMA

    #pragma unroll
    for (int ni = 0; ni < 4; ++ni) {
        const int c = c0 + ni * 16 + l15;
        const float bias = b1l[c] + b1r[c];
        #pragma unroll
        for (int mi = 0; mi < 4; ++mi) {
            #pragma unroll
            for (int i = 0; i < 4; ++i) {
                const int r = r0 + mi * 16 + l4 * 4 + i;
                if (r >= N_NODES) continue;
                h[(size_t)r * D_FEAT + c] = f2bf(fmaxf(acc[mi][ni][i] + bias, 0.f));
            }
        }
    }
}

// ---------------- GEMM2: u = h@W2l^T, v = h@W2r^T + b2 (fp32) ----------------
// 4 K-steps of BK=64, same pinned double-buffer pipeline. wave = 64r x 80c.
__global__ __launch_bounds__(256, 2)
void sage_gemm2_kernel(const unsigned short* __restrict__ hb,
                       const unsigned short* __restrict__ w2cat,
                       const float* __restrict__ b2l, const float* __restrict__ b2r,
                       float* __restrict__ u, float* __restrict__ v) {
    const int tid = threadIdx.x;
    const int wid = tid >> 6;
    const int lane = tid & 63;
    const int l15 = lane & 15, l4 = lane >> 4;
    const int r0 = blockIdx.x * 256 + wid * 64;

    int arow[4];
    #pragma unroll
    for (int mi = 0; mi < 4; ++mi) {
        int r = r0 + mi * 16 + l15;
        arow[mi] = (r < N_NODES) ? r : (N_NODES - 1);
    }

    f32x4 acc[4][5] = {};
    short8 a0[4][2], b0[5][2], a1[4][2], b1v[5][2];

#define G2_LOAD(aS, bS, s)                                                        \
    {                                                                             \
        const int kb_ = (s) * 64 + l4 * 8;                                        \
        _Pragma("unroll")                                                         \
        for (int ks = 0; ks < 2; ++ks) {                                          \
            _Pragma("unroll")                                                     \
            for (int mi = 0; mi < 4; ++mi)                                        \
                aS[mi][ks] = *reinterpret_cast<const short8*>(                    \
                    hb + (size_t)arow[mi] * D_FEAT + kb_ + ks * 32);              \
            _Pragma("unroll")                                                     \
            for (int ni = 0; ni < 5; ++ni)                                        \
                bS[ni][ks] = *reinterpret_cast<const short8*>(                    \
                    w2cat + (size_t)(ni * 16 + l15) * 256 + kb_ + ks * 32);       \
        }                                                                         \
    }

#define G2_MFMA(aS, bS)                                                           \
    _Pragma("unroll")                                                             \
    for (int ks = 0; ks < 2; ++ks)                                                \
        _Pragma("unroll")                                                         \
        for (int mi = 0; mi < 4; ++mi)                                            \
            _Pragma("unroll")                                                     \
            for (int ni = 0; ni < 5; ++ni)                                        \
                acc[mi][ni] = __builtin_amdgcn_mfma_f32_16x16x32_bf16(            \
                    aS[mi][ks], bS[ni][ks], acc[mi][ni], 0, 0, 0);

    G2_LOAD(a0, b0, 0)  SBAR();
    G2_LOAD(a1, b1v, 1) SBAR(); G2_MFMA(a0, b0)  SBAR();
    G2_LOAD(a0, b0, 2)  SBAR(); G2_MFMA(a1, b1v) SBAR();
    G2_LOAD(a1, b1v, 3) SBAR(); G2_MFMA(a0, b0)  SBAR();
    G2_MFMA(a1, b1v)
#undef G2_LOAD
#undef G2_MFMA

    #pragma unroll
    for (int ni = 0; ni < 5; ++ni) {
        const int c = ni * 16 + l15;             // 0..79
        const bool is_u = (c < N_CLASS);
        const float bias = is_u ? 0.f : (b2l[c - N_CLASS] + b2r[c - N_CLASS]);
        #pragma unroll
        for (int mi = 0; mi < 4; ++mi) {
            #pragma unroll
            for (int i = 0; i < 4; ++i) {
                const int r = r0 + mi * 16 + l4 * 4 + i;
                if (r >= N_NODES) continue;
                const float val = acc[mi][ni][i] + bias;
                if (is_u) u[(size_t)r * N_CLASS + c] = val;
                else      v[(size_t)r * N_CLASS + (c - N_CLASS)] = val;
            }
        }
    }
}

// ---------------- gather2: out = agg(u) + v  (40-dim), 4-way unrolled ----------------
__global__ __launch_bounds__(256)
void sage_gather2_kernel(const float* __restrict__ u, const float* __restrict__ v,
                         const int* __restrict__ row_off, const int* __restrict__ csr,
                         float* __restrict__ out) {
    const int node = blockIdx.x * 4 + (threadIdx.x >> 6);
    const int lane = threadIdx.x & 63;
    if (node >= N_NODES || lane >= N_CLASS) return;
    const int k0 = row_off[node];
    const int k1 = row_off[node + 1];
    float a = 0.f;
    int k = k0;
    for (; k + 4 <= k1; k += 4) {
        const int s0 = csr[k], s1 = csr[k + 1], s2 = csr[k + 2], s3 = csr[k + 3];
        const float f0 = u[(size_t)s0 * N_CLASS + lane];
        const float f1 = u[(size_t)s1 * N_CLASS + lane];
        const float f2 = u[(size_t)s2 * N_CLASS + lane];
        const float f3 = u[(size_t)s3 * N_CLASS + lane];
        SBAR();
        a += f0 + f1 + f2 + f3;
    }
    for (; k < k1; ++k)
        a += u[(size_t)csr[k] * N_CLASS + lane];
    const float sc = 1.0f / fmaxf((float)(k1 - k0), 1.0f);
    out[(size_t)node * N_CLASS + lane] = a * sc + v[(size_t)node * N_CLASS + lane];
}

extern "C" void kernel_launch(void* const* d_in, const int* in_sizes, int n_in,
                              void* d_out, int out_size, void* d_ws, size_t ws_size,
                              hipStream_t stream) {
    const float* x    = (const float*)d_in[0];
    const int*   ei   = (const int*)d_in[1];
    const float* w1l  = (const float*)d_in[2];
    const float* b1l  = (const float*)d_in[3];
    const float* w1r  = (const float*)d_in[4];
    const float* b1r  = (const float*)d_in[5];
    const float* w2l  = (const float*)d_in[6];
    const float* b2l  = (const float*)d_in[7];
    const float* w2r  = (const float*)d_in[8];
    const float* b2r  = (const float*)d_in[9];
    float* out = (float*)d_out;

    const int* src = ei;
    const int* dst = ei + N_EDGES;

    // workspace layout (bytes)
    const size_t FEAT_BYTES  = (size_t)N_NODES * D_FEAT * 2;           // 25.6 MB
    const size_t ROW_OFF_OFF = 0;
    const size_t CURSOR_OFF  = 204800;
    const size_t BSUM_OFF    = 409600;
    const size_t CSR_OFF     = 410624;
    const size_t XB_OFF      = CSR_OFF + (size_t)N_EDGES * 4 + 1024;   // 3,611,648
    const size_t AGG_OFF     = XB_OFF + FEAT_BYTES;
    const size_t H_OFF       = AGG_OFF + FEAT_BYTES;
    const size_t W1C_OFF     = H_OFF + FEAT_BYTES;
    const size_t W2C_OFF     = W1C_OFF + 262144;
    const size_t U_OFF       = W2C_OFF + 40960;
    const size_t V_OFF       = U_OFF + (size_t)N_NODES * N_CLASS * 4;

    int* row_off = (int*)((char*)d_ws + ROW_OFF_OFF);
    int* cursor  = (int*)((char*)d_ws + CURSOR_OFF);
    int* bsum    = (int*)((char*)d_ws + BSUM_OFF);
    int* csr     = (int*)((char*)d_ws + CSR_OFF);
    unsigned short* xb    = (unsigned short*)((char*)d_ws + XB_OFF);
    unsigned short* aggb  = (unsigned short*)((char*)d_ws + AGG_OFF);
    unsigned short* hb    = (unsigned short*)((char*)d_ws + H_OFF);
    unsigned short* w1cat = (unsigned short*)((char*)d_ws + W1C_OFF);
    unsigned short* w2cat = (unsigned short*)((char*)d_ws + W2C_OFF);
    float* u = (float*)((char*)d_ws + U_OFF);
    float* v = (float*)((char*)d_ws + V_OFF);

    const int eblocks = (N_EDGES + 255) / 256;     // 3125
    const int gblocks = (N_NODES + 7) / 8;         // 6250

    // ---- converts ----
    cvt_bf16_kernel<<<(N_NODES * D_FEAT / 4 + 255) / 256, 256, 0, stream>>>(x, xb, N_NODES * D_FEAT / 4);
    cvt_weights_kernel<<<148, 256, 0, stream>>>(w1l, w1r, w2l, w2r, w1cat, w2cat);

    // ---- CSR build ----
    hipMemsetAsync(cursor, 0, (size_t)N_NODES * 4, stream);
    sage_deg_kernel<<<eblocks, 256, 0, stream>>>(dst, cursor);
    scan_local_kernel<<<NSCAN_BLOCKS, 256, 0, stream>>>(cursor, row_off, bsum);
    scan_bsum_kernel<<<1, 256, 0, stream>>>(bsum, row_off);
    scan_add_kernel<<<NSCAN_BLOCKS, 256, 0, stream>>>(row_off, bsum, row_off, cursor);
    sage_fill_kernel<<<eblocks, 256, 0, stream>>>(src, dst, cursor, csr);

    // ---- layer 1 ----
    sage_gather_kernel<<<gblocks, 256, 0, stream>>>(xb, row_off, csr, aggb);
    sage_gemm1_kernel<<<784, 256, 0, stream>>>(aggb, xb, w1cat, b1l, b1r, hb);

    // ---- layer 2 (transform-then-aggregate) ----
    sage_gemm2_kernel<<<196, 256, 0, stream>>>(hb, w2cat, b2l, b2r, u, v);
    sage_gather2_kernel<<<(N_NODES + 3) / 4, 256, 0, stream>>>(u, v, row_off, csr, out);

    (void)in_sizes; (void)n_in; (void)out_size; (void)ws_size;
}

// Round 8
// 244.180 us; speedup vs baseline: 1.3484x; 1.1454x over previous
//
#include <hip/hip_runtime.h>

#define N_NODES 50000
#define N_EDGES 800000
#define D_FEAT  256
#define N_CLASS 40
#define NSCAN_BLOCKS ((N_NODES + 255) / 256)   // 196

typedef __attribute__((ext_vector_type(8))) short short8;
typedef __attribute__((ext_vector_type(4))) float f32x4;

#define SBAR() __builtin_amdgcn_sched_barrier(0)

__device__ __forceinline__ float bf2f(unsigned short u) {
    unsigned int x = ((unsigned int)u) << 16;
    return __builtin_bit_cast(float, x);
}
__device__ __forceinline__ unsigned short f2bf(float f) {
    unsigned int x = __builtin_bit_cast(unsigned int, f);
    x += 0x7fff + ((x >> 16) & 1);   // RTNE
    return (unsigned short)(x >> 16);
}

// ---------------- fp32 -> bf16 convert (x) ----------------
__global__ void cvt_bf16_kernel(const float* __restrict__ in, unsigned short* __restrict__ out, int n4) {
    int i = blockIdx.x * blockDim.x + threadIdx.x;
    if (i >= n4) return;
    float4 v = reinterpret_cast<const float4*>(in)[i];
    ushort4 o;
    o.x = f2bf(v.x); o.y = f2bf(v.y); o.z = f2bf(v.z); o.w = f2bf(v.w);
    reinterpret_cast<ushort4*>(out)[i] = o;
}

// ---------------- weight converts -> concatenated bf16 layouts ----------------
// w1cat: [256][512]  row c = [W1l[c][0:256] | W1r[c][0:256]]
// w2cat: [80][256]   rows 0-39 = W2l, rows 40-79 = W2r
__global__ void cvt_weights_kernel(const float* __restrict__ w1l, const float* __restrict__ w1r,
                                   const float* __restrict__ w2l, const float* __restrict__ w2r,
                                   unsigned short* __restrict__ w1cat, unsigned short* __restrict__ w2cat) {
    int i = blockIdx.x * blockDim.x + threadIdx.x;   // float4 index
    const int N1 = 256 * 128;
    const int N2 = 80 * 64;
    const float* s; unsigned short* dptr;
    if (i < N1) {
        int n = i >> 7, kq = i & 127;
        s = (kq < 64) ? (w1l + n * 256 + kq * 4) : (w1r + n * 256 + (kq - 64) * 4);
        dptr = w1cat + n * 512 + kq * 4;
    } else if (i < N1 + N2) {
        int j = i - N1;
        int n = j >> 6, kq = j & 63;
        s = (n < 40) ? (w2l + n * 256 + kq * 4) : (w2r + (n - 40) * 256 + kq * 4);
        dptr = w2cat + n * 256 + kq * 4;
    } else return;
    float4 v = *reinterpret_cast<const float4*>(s);
    ushort4 o;
    o.x = f2bf(v.x); o.y = f2bf(v.y); o.z = f2bf(v.z); o.w = f2bf(v.w);
    *reinterpret_cast<ushort4*>(dptr) = o;
}

// ---------------- degree histogram ----------------
__global__ void sage_deg_kernel(const int* __restrict__ dst, int* __restrict__ degc) {
    int e = blockIdx.x * blockDim.x + threadIdx.x;
    if (e < N_EDGES) atomicAdd(&degc[dst[e]], 1);
}

// ---------------- hierarchical scan ----------------
__global__ __launch_bounds__(256)
void scan_local_kernel(const int* __restrict__ deg, int* __restrict__ escan, int* __restrict__ bsum) {
    __shared__ int s[256];
    const int t = threadIdx.x;
    const int i = blockIdx.x * 256 + t;
    const int v = (i < N_NODES) ? deg[i] : 0;
    s[t] = v;
    __syncthreads();
    #pragma unroll
    for (int off = 1; off < 256; off <<= 1) {
        int u = (t >= off) ? s[t - off] : 0;
        __syncthreads();
        s[t] += u;
        __syncthreads();
    }
    if (i < N_NODES) escan[i] = s[t] - v;
    if (t == 255) bsum[blockIdx.x] = s[255];
}

__global__ __launch_bounds__(256)
void scan_bsum_kernel(int* __restrict__ bsum, int* __restrict__ row_off) {
    __shared__ int s[256];
    const int t = threadIdx.x;
    const int v = (t < NSCAN_BLOCKS) ? bsum[t] : 0;
    s[t] = v;
    __syncthreads();
    #pragma unroll
    for (int off = 1; off < 256; off <<= 1) {
        int u = (t >= off) ? s[t - off] : 0;
        __syncthreads();
        s[t] += u;
        __syncthreads();
    }
    if (t < NSCAN_BLOCKS) bsum[t] = s[t] - v;
    if (t == 255) row_off[N_NODES] = s[255];
}

__global__ void scan_add_kernel(const int* __restrict__ escan_in, const int* __restrict__ bsum,
                                int* __restrict__ row_off, int* __restrict__ cursor) {
    const int i = blockIdx.x * 256 + threadIdx.x;
    if (i >= N_NODES) return;
    const int v = escan_in[i] + bsum[blockIdx.x];
    row_off[i] = v;
    cursor[i] = v;
}

// ---------------- CSR fill ----------------
__global__ void sage_fill_kernel(const int* __restrict__ src, const int* __restrict__ dst,
                                 int* __restrict__ cursor, int* __restrict__ csr) {
    int e = blockIdx.x * blockDim.x + threadIdx.x;
    if (e >= N_EDGES) return;
    int pos = atomicAdd(&cursor[dst[e]], 1);
    csr[pos] = src[e];
}

// ---------------- bf16 gather-aggregate + mean (256-dim, layer 1) ----------------
__global__ __launch_bounds__(256)
void sage_gather_kernel(const unsigned short* __restrict__ feat,
                        const int* __restrict__ row_off,
                        const int* __restrict__ csr,
                        unsigned short* __restrict__ agg) {
    const int tid = threadIdx.x;
    const int lane = tid & 63;
    const int node = blockIdx.x * 8 + (tid >> 6) * 2 + (lane >> 5);
    const int c8 = (lane & 31) * 8;
    if (node >= N_NODES) return;
    const int k0 = row_off[node];
    const int k1 = row_off[node + 1];
    float a[8] = {};
    int k = k0;
    for (; k + 4 <= k1; k += 4) {
        const int s0 = csr[k], s1 = csr[k + 1], s2 = csr[k + 2], s3 = csr[k + 3];
        short8 v0 = *reinterpret_cast<const short8*>(feat + (size_t)s0 * D_FEAT + c8);
        short8 v1 = *reinterpret_cast<const short8*>(feat + (size_t)s1 * D_FEAT + c8);
        short8 v2 = *reinterpret_cast<const short8*>(feat + (size_t)s2 * D_FEAT + c8);
        short8 v3 = *reinterpret_cast<const short8*>(feat + (size_t)s3 * D_FEAT + c8);
        SBAR();
        #pragma unroll
        for (int j = 0; j < 8; ++j)
            a[j] += bf2f((unsigned short)v0[j]) + bf2f((unsigned short)v1[j])
                  + bf2f((unsigned short)v2[j]) + bf2f((unsigned short)v3[j]);
    }
    for (; k < k1; ++k) {
        const int s = csr[k];
        short8 v = *reinterpret_cast<const short8*>(feat + (size_t)s * D_FEAT + c8);
        #pragma unroll
        for (int j = 0; j < 8; ++j) a[j] += bf2f((unsigned short)v[j]);
    }
    const float sc = 1.0f / fmaxf((float)(k1 - k0), 1.0f);
    short8 o;
    #pragma unroll
    for (int j = 0; j < 8; ++j) o[j] = (short)f2bf(a[j] * sc);
    *reinterpret_cast<short8*>(agg + (size_t)node * D_FEAT + c8) = o;
}

// ---------------- GEMM1: h = relu([agg|x] @ w1cat^T + b1), weights-stationary ----------------
// Tile 256 rows x 64 cols; w1cat 64-col slice staged once into 64KB swizzled LDS;
// barrier-free K loop: 16 steps of {4 global A loads (3-buf, 2 ahead) | 4 ds_reads (2-buf,
// 1 ahead) | 16 MFMA}, pinned with sched_barrier. Grid 784 linear, XCD-chunked.
__global__ __launch_bounds__(256, 2)
void sage_gemm1_kernel(const unsigned short* __restrict__ agg,
                       const unsigned short* __restrict__ xb,
                       const unsigned short* __restrict__ w1cat,
                       const float* __restrict__ b1l, const float* __restrict__ b1r,
                       unsigned short* __restrict__ h) {
    __shared__ unsigned short Bl[64 * 512];   // 64 KB

    const int t = (blockIdx.x & 7) * 98 + (blockIdx.x >> 3);   // bijective: 784 = 8*98
    const int xblk = t >> 2;          // 0..195 row-block (256 rows)
    const int yblk = t & 3;           // 0..3 col-block (64 cols)
    const int c0 = yblk * 64;

    const int tid = threadIdx.x;
    const int wid = tid >> 6;
    const int lane = tid & 63;
    const int l15 = lane & 15, l4 = lane >> 4;
    const int r0 = xblk * 256 + wid * 64;

    // ---- stage B slice (64 cols x 512 k), XOR-swizzled: byte ^= (col&7)<<4 ----
    #pragma unroll
    for (int r = 0; r < 16; ++r) {
        const int idx = r * 256 + tid;            // 0..4095 chunks of 16B
        const int cl = idx >> 6, kc = idx & 63;   // col-local, k-chunk
        short8 v = *reinterpret_cast<const short8*>(w1cat + (size_t)(c0 + cl) * 512 + kc * 8);
        *reinterpret_cast<short8*>((char*)Bl + cl * 1024 + ((kc * 16) ^ ((cl & 7) << 4))) = v;
    }
    __syncthreads();

    int arow[4];
    #pragma unroll
    for (int mi = 0; mi < 4; ++mi) {
        int r = r0 + mi * 16 + l15;
        arow[mi] = (r < N_NODES) ? r : (N_NODES - 1);
    }

    f32x4 acc[4][4] = {};
    short8 aA[4], aB[4], aC[4], bA[4], bB[4];

#define LA(buf, s)                                                                 \
    {                                                                              \
        const unsigned short* As_ = ((s) < 8) ? agg : xb;                          \
        const int kb_ = ((s) & 7) * 32 + l4 * 8;                                   \
        _Pragma("unroll")                                                          \
        for (int mi = 0; mi < 4; ++mi)                                             \
            buf[mi] = *reinterpret_cast<const short8*>(                            \
                As_ + (size_t)arow[mi] * D_FEAT + kb_);                            \
    }
#define LB(buf, s)                                                                 \
    {                                                                              \
        _Pragma("unroll")                                                          \
        for (int ni = 0; ni < 4; ++ni) {                                           \
            const int cl_ = ni * 16 + l15;                                         \
            buf[ni] = *reinterpret_cast<const short8*>(                            \
                (const char*)Bl + cl_ * 1024 +                                     \
                (((s) * 64 + l4 * 16) ^ ((cl_ & 7) << 4)));                        \
        }                                                                          \
    }
#define MM(ab, bb)                                                                 \
    _Pragma("unroll")                                                              \
    for (int mi = 0; mi < 4; ++mi)                                                 \
        _Pragma("unroll")                                                          \
        for (int ni = 0; ni < 4; ++ni)                                             \
            acc[mi][ni] = __builtin_amdgcn_mfma_f32_16x16x32_bf16(                 \
                ab[mi], bb[ni], acc[mi][ni], 0, 0, 0);

    LA(aA, 0) LA(aB, 1) LB(bA, 0) SBAR();
    LA(aC, 2)  LB(bB, 1)  SBAR(); MM(aA, bA) SBAR();
    LA(aA, 3)  LB(bA, 2)  SBAR(); MM(aB, bB) SBAR();
    LA(aB, 4)  LB(bB, 3)  SBAR(); MM(aC, bA) SBAR();
    LA(aC, 5)  LB(bA, 4)  SBAR(); MM(aA, bB) SBAR();
    LA(aA, 6)  LB(bB, 5)  SBAR(); MM(aB, bA) SBAR();
    LA(aB, 7)  LB(bA, 6)  SBAR(); MM(aC, bB) SBAR();
    LA(aC, 8)  LB(bB, 7)  SBAR(); MM(aA, bA) SBAR();
    LA(aA, 9)  LB(bA, 8)  SBAR(); MM(aB, bB) SBAR();
    LA(aB, 10) LB(bB, 9)  SBAR(); MM(aC, bA) SBAR();
    LA(aC, 11) LB(bA, 10) SBAR(); MM(aA, bB) SBAR();
    LA(aA, 12) LB(bB, 11) SBAR(); MM(aB, bA) SBAR();
    LA(aB, 13) LB(bA, 12) SBAR(); MM(aC, bB) SBAR();
    LA(aC, 14) LB(bB, 13) SBAR(); MM(aA, bA) SBAR();
    LA(aA, 15) LB(bA, 14) SBAR(); MM(aB, bB) SBAR();
    LB(bB, 15) SBAR();            MM(aC, bA) SBAR();
    MM(aA, bB)
#undef LA
#undef LB
#undef MM

    #pragma unroll
    for (int ni = 0; ni < 4; ++ni) {
        const int c = c0 + ni * 16 + l15;
        const float bias = b1l[c] + b1r[c];
        #pragma unroll
        for (int mi = 0; mi < 4; ++mi) {
            #pragma unroll
            for (int i = 0; i < 4; ++i) {
                const int r = r0 + mi * 16 + l4 * 4 + i;
                if (r >= N_NODES) continue;
                h[(size_t)r * D_FEAT + c] = f2bf(fmaxf(acc[mi][ni][i] + bias, 0.f));
            }
        }
    }
}

// ---------------- GEMM2: u = h@W2l^T, v = h@W2r^T + b2 (fp32), weights-stationary ----------------
// Whole w2cat (80 cols x 256 k = 40KB) in swizzled LDS; 8 barrier-free K-steps.
__global__ __launch_bounds__(256, 2)
void sage_gemm2_kernel(const unsigned short* __restrict__ hb,
                       const unsigned short* __restrict__ w2cat,
                       const float* __restrict__ b2l, const float* __restrict__ b2r,
                       float* __restrict__ u, float* __restrict__ v) {
    __shared__ unsigned short Bl[80 * 256];   // 40 KB

    const int tid = threadIdx.x;
    const int wid = tid >> 6;
    const int lane = tid & 63;
    const int l15 = lane & 15, l4 = lane >> 4;
    const int r0 = blockIdx.x * 256 + wid * 64;

    // stage all of w2cat: 2560 chunks of 16B
    #pragma unroll
    for (int r = 0; r < 10; ++r) {
        const int idx = r * 256 + tid;            // 0..2559
        const int cl = idx >> 5, kc = idx & 31;
        short8 vch = *reinterpret_cast<const short8*>(w2cat + (size_t)cl * 256 + kc * 8);
        *reinterpret_cast<short8*>((char*)Bl + cl * 512 + ((kc * 16) ^ ((cl & 7) << 4))) = vch;
    }
    __syncthreads();

    int arow[4];
    #pragma unroll
    for (int mi = 0; mi < 4; ++mi) {
        int r = r0 + mi * 16 + l15;
        arow[mi] = (r < N_NODES) ? r : (N_NODES - 1);
    }

    f32x4 acc[4][5] = {};
    short8 aA[4], aB[4], aC[4], bA[5], bB[5];

#define LA2(buf, s)                                                                \
    {                                                                              \
        const int kb_ = (s) * 32 + l4 * 8;                                         \
        _Pragma("unroll")                                                          \
        for (int mi = 0; mi < 4; ++mi)                                             \
            buf[mi] = *reinterpret_cast<const short8*>(                            \
                hb + (size_t)arow[mi] * D_FEAT + kb_);                             \
    }
#define LB2(buf, s)                                                                \
    {                                                                              \
        _Pragma("unroll")                                                          \
        for (int ni = 0; ni < 5; ++ni) {                                           \
            const int cl_ = ni * 16 + l15;                                         \
            buf[ni] = *reinterpret_cast<const short8*>(                            \
                (const char*)Bl + cl_ * 512 +                                      \
                (((s) * 64 + l4 * 16) ^ ((cl_ & 7) << 4)));                        \
        }                                                                          \
    }
#define MM2(ab, bb)                                                                \
    _Pragma("unroll")                                                              \
    for (int mi = 0; mi < 4; ++mi)                                                 \
        _Pragma("unroll")                                                          \
        for (int ni = 0; ni < 5; ++ni)                                             \
            acc[mi][ni] = __builtin_amdgcn_mfma_f32_16x16x32_bf16(                 \
                ab[mi], bb[ni], acc[mi][ni], 0, 0, 0);

    LA2(aA, 0) LA2(aB, 1) LB2(bA, 0) SBAR();
    LA2(aC, 2) LB2(bB, 1) SBAR(); MM2(aA, bA) SBAR();
    LA2(aA, 3) LB2(bA, 2) SBAR(); MM2(aB, bB) SBAR();
    LA2(aB, 4) LB2(bB, 3) SBAR(); MM2(aC, bA) SBAR();
    LA2(aC, 5) LB2(bA, 4) SBAR(); MM2(aA, bB) SBAR();
    LA2(aA, 6) LB2(bB, 5) SBAR(); MM2(aB, bA) SBAR();
    LA2(aB, 7) LB2(bA, 6) SBAR(); MM2(aC, bB) SBAR();
    LB2(bB, 7) SBAR();            MM2(aA, bA) SBAR();
    MM2(aB, bB)
#undef LA2
#undef LB2
#undef MM2

    #pragma unroll
    for (int ni = 0; ni < 5; ++ni) {
        const int c = ni * 16 + l15;             // 0..79
        const bool is_u = (c < N_CLASS);
        const float bias = is_u ? 0.f : (b2l[c - N_CLASS] + b2r[c - N_CLASS]);
        #pragma unroll
        for (int mi = 0; mi < 4; ++mi) {
            #pragma unroll
            for (int i = 0; i < 4; ++i) {
                const int r = r0 + mi * 16 + l4 * 4 + i;
                if (r >= N_NODES) continue;
                const float val = acc[mi][ni][i] + bias;
                if (is_u) u[(size_t)r * N_CLASS + c] = val;
                else      v[(size_t)r * N_CLASS + (c - N_CLASS)] = val;
            }
        }
    }
}

// ---------------- gather2: out = agg(u) + v  (40-dim), 4-way unrolled ----------------
__global__ __launch_bounds__(256)
void sage_gather2_kernel(const float* __restrict__ u, const float* __restrict__ v,
                         const int* __restrict__ row_off, const int* __restrict__ csr,
                         float* __restrict__ out) {
    const int node = blockIdx.x * 4 + (threadIdx.x >> 6);
    const int lane = threadIdx.x & 63;
    if (node >= N_NODES || lane >= N_CLASS) return;
    const int k0 = row_off[node];
    const int k1 = row_off[node + 1];
    float a = 0.f;
    int k = k0;
    for (; k + 4 <= k1; k += 4) {
        const int s0 = csr[k], s1 = csr[k + 1], s2 = csr[k + 2], s3 = csr[k + 3];
        const float f0 = u[(size_t)s0 * N_CLASS + lane];
        const float f1 = u[(size_t)s1 * N_CLASS + lane];
        const float f2 = u[(size_t)s2 * N_CLASS + lane];
        const float f3 = u[(size_t)s3 * N_CLASS + lane];
        SBAR();
        a += f0 + f1 + f2 + f3;
    }
    for (; k < k1; ++k)
        a += u[(size_t)csr[k] * N_CLASS + lane];
    const float sc = 1.0f / fmaxf((float)(k1 - k0), 1.0f);
    out[(size_t)node * N_CLASS + lane] = a * sc + v[(size_t)node * N_CLASS + lane];
}

extern "C" void kernel_launch(void* const* d_in, const int* in_sizes, int n_in,
                              void* d_out, int out_size, void* d_ws, size_t ws_size,
                              hipStream_t stream) {
    const float* x    = (const float*)d_in[0];
    const int*   ei   = (const int*)d_in[1];
    const float* w1l  = (const float*)d_in[2];
    const float* b1l  = (const float*)d_in[3];
    const float* w1r  = (const float*)d_in[4];
    const float* b1r  = (const float*)d_in[5];
    const float* w2l  = (const float*)d_in[6];
    const float* b2l  = (const float*)d_in[7];
    const float* w2r  = (const float*)d_in[8];
    const float* b2r  = (const float*)d_in[9];
    float* out = (float*)d_out;

    const int* src = ei;
    const int* dst = ei + N_EDGES;

    // workspace layout (bytes)
    const size_t FEAT_BYTES  = (size_t)N_NODES * D_FEAT * 2;           // 25.6 MB
    const size_t ROW_OFF_OFF = 0;
    const size_t CURSOR_OFF  = 204800;
    const size_t BSUM_OFF    = 409600;
    const size_t CSR_OFF     = 410624;
    const size_t XB_OFF      = CSR_OFF + (size_t)N_EDGES * 4 + 1024;   // 3,611,648
    const size_t AGG_OFF     = XB_OFF + FEAT_BYTES;
    const size_t H_OFF       = AGG_OFF + FEAT_BYTES;
    const size_t W1C_OFF     = H_OFF + FEAT_BYTES;
    const size_t W2C_OFF     = W1C_OFF + 262144;
    const size_t U_OFF       = W2C_OFF + 40960;
    const size_t V_OFF       = U_OFF + (size_t)N_NODES * N_CLASS * 4;

    int* row_off = (int*)((char*)d_ws + ROW_OFF_OFF);
    int* cursor  = (int*)((char*)d_ws + CURSOR_OFF);
    int* bsum    = (int*)((char*)d_ws + BSUM_OFF);
    int* csr     = (int*)((char*)d_ws + CSR_OFF);
    unsigned short* xb    = (unsigned short*)((char*)d_ws + XB_OFF);
    unsigned short* aggb  = (unsigned short*)((char*)d_ws + AGG_OFF);
    unsigned short* hb    = (unsigned short*)((char*)d_ws + H_OFF);
    unsigned short* w1cat = (unsigned short*)((char*)d_ws + W1C_OFF);
    unsigned short* w2cat = (unsigned short*)((char*)d_ws + W2C_OFF);
    float* u = (float*)((char*)d_ws + U_OFF);
    float* v = (float*)((char*)d_ws + V_OFF);

    const int eblocks = (N_EDGES + 255) / 256;     // 3125
    const int gblocks = (N_NODES + 7) / 8;         // 6250

    // ---- converts ----
    cvt_bf16_kernel<<<(N_NODES * D_FEAT / 4 + 255) / 256, 256, 0, stream>>>(x, xb, N_NODES * D_FEAT / 4);
    cvt_weights_kernel<<<148, 256, 0, stream>>>(w1l, w1r, w2l, w2r, w1cat, w2cat);

    // ---- CSR build ----
    hipMemsetAsync(cursor, 0, (size_t)N_NODES * 4, stream);
    sage_deg_kernel<<<eblocks, 256, 0, stream>>>(dst, cursor);
    scan_local_kernel<<<NSCAN_BLOCKS, 256, 0, stream>>>(cursor, row_off, bsum);
    scan_bsum_kernel<<<1, 256, 0, stream>>>(bsum, row_off);
    scan_add_kernel<<<NSCAN_BLOCKS, 256, 0, stream>>>(row_off, bsum, row_off, cursor);
    sage_fill_kernel<<<eblocks, 256, 0, stream>>>(src, dst, cursor, csr);

    // ---- layer 1 ----
    sage_gather_kernel<<<gblocks, 256, 0, stream>>>(xb, row_off, csr, aggb);
    sage_gemm1_kernel<<<784, 256, 0, stream>>>(aggb, xb, w1cat, b1l, b1r, hb);

    // ---- layer 2 (transform-then-aggregate) ----
    sage_gemm2_kernel<<<196, 256, 0, stream>>>(hb, w2cat, b2l, b2r, u, v);
    sage_gather2_kernel<<<(N_NODES + 3) / 4, 256, 0, stream>>>(u, v, row_off, csr, out);

    (void)in_sizes; (void)n_in; (void)out_size; (void)ws_size;
}